// Round 3
// baseline (290.377 us; speedup 1.0000x reference)
//
#include <hip/hip_runtime.h>
#include <math.h>

#define N_NODES 2048
#define NNE ((long)N_NODES * N_NODES)   // elems per channel matrix

// f16 two-term split: x ~= h + l (true residual). Three MFMA products
// (hh, lh, hl) into ONE fp32 accumulator; dropped l*l term ~2^-22 relative.
// Scale chain (all powers of 2, exact):
//   V0' = supd * 2^13
//   T0  = Hc@V0'  -> scaled by sT0[f] = 2^(10-ilogb(cn0[f])), cn0=sum_m|V0'|
//   T1  = Hb@T0'  -> scaled by sT1[f] = 2^(10-ilogb(cn1[f])), cn1=sum_j|T0'|
//   T2  = Ha@T1'  (fp32); out = d*(T2*2^(i0+i1-33) + supd) + b
// H matrices never materialized: gemm_mix_k mixes A->H on the fly.
// R3: one channel per block, split-K 2 (partials 67->8 MB), XCD-paired grid.
#define SUPD_SCALE 8192.0f

typedef _Float16 half4_t __attribute__((ext_vector_type(4)));
typedef _Float16 half8_t __attribute__((ext_vector_type(8)));
typedef float    floatx4 __attribute__((ext_vector_type(4)));

__device__ __forceinline__ void async_cp16(const void* g, void* l) {
  __builtin_amdgcn_global_load_lds((const __attribute__((address_space(1))) void*)g,
                                   (__attribute__((address_space(3))) void*)l,
                                   16, 0, 0);
}

__device__ __forceinline__ float colscale_from(float cn) {
  return exp2f((float)(10 - ilogbf(fmaxf(cn, 1e-37f))));
}

// ---- softmax of the three 4x4 weight matrices + zero cn0/cn1 (1024 f) ----
__global__ void softmax3_zero_k(const float* __restrict__ w1,
                                const float* __restrict__ w2,
                                const float* __restrict__ w3,
                                float* __restrict__ fw,
                                float* __restrict__ cn) {
  int t = threadIdx.x;
  float4 z4 = {0.f, 0.f, 0.f, 0.f};
  ((float4*)cn)[t] = z4;                       // 256*4 = 1024 floats
  if (t < 12) {
    const float* src = (t < 4) ? w1 : (t < 8) ? w2 : w3;
    int r = t & 3;
    float v0 = src[r * 4 + 0], v1 = src[r * 4 + 1];
    float v2 = src[r * 4 + 2], v3 = src[r * 4 + 3];
    float m = fmaxf(fmaxf(v0, v1), fmaxf(v2, v3));
    float e0 = expf(v0 - m), e1 = expf(v1 - m), e2 = expf(v2 - m), e3 = expf(v3 - m);
    float inv = 1.0f / (e0 + e1 + e2 + e3);
    fw[t * 4 + 0] = e0 * inv; fw[t * 4 + 1] = e1 * inv;
    fw[t * 4 + 2] = e2 * inv; fw[t * 4 + 3] = e3 * inv;
  }
}

// ---------------- support = X @ gcn_w  [2048,256]@[256,128] ----------------
__global__ __launch_bounds__(128)
void support_k(const float* __restrict__ X, const float* __restrict__ W,
               float* __restrict__ sup) {
  __shared__ float Xs[256];
  const int t = threadIdx.x;
  const int m = blockIdx.x;
  Xs[t]       = X[(long)m * 256 + t];
  Xs[t + 128] = X[(long)m * 256 + t + 128];
  __syncthreads();
  float acc = 0.f;
  #pragma unroll 8
  for (int k = 0; k < 256; ++k) acc = fmaf(Xs[k], W[(long)k * 128 + t], acc);
  sup[(long)m * 128 + t] = acc;
}

// ---- rc[c][r] = sum_e fw3[c][e] * rowsum(A_e)[r]   (one A pass) ----------
__global__ __launch_bounds__(256)
void rc_from_A_k(const float* __restrict__ A, const float* __restrict__ fw,
                 float* __restrict__ rc) {
  const int wave = threadIdx.x >> 6, lane = threadIdx.x & 63;
  const int r = blockIdx.x * 4 + wave;
  float se[4];
  #pragma unroll
  for (int e = 0; e < 4; ++e) {
    const float4* row = (const float4*)(A + (long)e * NNE + (long)r * N_NODES);
    float s = 0.f;
    for (int j4 = lane; j4 < 512; j4 += 64) {
      float4 a = row[j4];
      s += (a.x + a.y) + (a.z + a.w);
    }
    for (int o = 32; o > 0; o >>= 1) s += __shfl_down(s, o, 64);
    se[e] = s;
  }
  if (lane == 0) {
    #pragma unroll
    for (int c = 0; c < 4; ++c)
      rc[c * N_NODES + r] = fw[32 + c * 4 + 0] * se[0] + fw[32 + c * 4 + 1] * se[1] +
                            fw[32 + c * 4 + 2] * se[2] + fw[32 + c * 4 + 3] * se[3];
  }
}

// -- vout[c][r] = sum_e fw[off+c*4+e] * (A_e @ vin[c])[r]  (fp32, one A pass)
__global__ __launch_bounds__(256)
void matvecA_k(const float* __restrict__ A, const float* __restrict__ fw, int off,
               const float* __restrict__ vin, float* __restrict__ vout) {
  __shared__ float vs[4 * 2048];
  const int t = threadIdx.x;
  for (int i = t; i < 4 * 2048; i += 256) vs[i] = vin[i];
  __syncthreads();
  const int wave = t >> 6, lane = t & 63;
  const int r = blockIdx.x * 4 + wave;
  float acc[4][4] = {{0.f}};
  #pragma unroll
  for (int e = 0; e < 4; ++e) {
    const float4* row = (const float4*)(A + (long)e * NNE + (long)r * N_NODES);
    for (int j4 = lane; j4 < 512; j4 += 64) {
      float4 a = row[j4];
      #pragma unroll
      for (int c = 0; c < 4; ++c) {
        const float4 v = *(const float4*)&vs[c * 2048 + j4 * 4];
        acc[e][c] += (a.x * v.x + a.y * v.y) + (a.z * v.z + a.w * v.w);
      }
    }
  }
  #pragma unroll
  for (int e = 0; e < 4; ++e)
    #pragma unroll
    for (int c = 0; c < 4; ++c)
      for (int o = 32; o > 0; o >>= 1) acc[e][c] += __shfl_down(acc[e][c], o, 64);
  if (lane == 0) {
    #pragma unroll
    for (int c = 0; c < 4; ++c) {
      float s = fw[off + c * 4 + 0] * acc[0][c] + fw[off + c * 4 + 1] * acc[1][c] +
                fw[off + c * 4 + 2] * acc[2][c] + fw[off + c * 4 + 3] * acc[3][c];
      vout[c * N_NODES + r] = s;
    }
  }
}

// -- fused: dm = 1/sqrt(1+deg); supd = dm*sup (side output, + dvec);
// -- VT[z][f][m] = split( supd*2^13 ); cn0[z][f] += sum_m |val| ------------
__global__ __launch_bounds__(256)
void transposeV_k(const float* __restrict__ sup, const float* __restrict__ deg,
                  float* __restrict__ dvec, float* __restrict__ supd,
                  _Float16* __restrict__ TH, _Float16* __restrict__ TL,
                  float* __restrict__ cn0) {
  __shared__ _Float16 sh[32][33], sl[32][33];
  __shared__ float red[8][32];
  const int t = threadIdx.x;
  const int z = blockIdx.z;
  const int m0 = blockIdx.x * 32, f0 = blockIdx.y * 32;
  const int r0 = t >> 5, col = t & 31;
  float part = 0.f;
  #pragma unroll
  for (int m = 0; m < 4; ++m) {
    const int row = m0 + r0 + 8 * m;
    float dm = 1.0f / sqrtf(1.0f + deg[(long)z * N_NODES + row]);
    float sv = sup[(long)row * 128 + f0 + col] * dm;
    supd[((long)z * N_NODES + row) * 128 + f0 + col] = sv;
    if (blockIdx.y == 0 && col == 0) dvec[(long)z * N_NODES + row] = dm;
    float v = sv * SUPD_SCALE;
    _Float16 h = (_Float16)v;
    sh[r0 + 8 * m][col] = h;
    sl[r0 + 8 * m][col] = (_Float16)(v - (float)h);
    part += fabsf(v);
  }
  red[r0][col] = part;
  __syncthreads();
  if (t < 32) {
    float s = 0.f;
    #pragma unroll
    for (int q = 0; q < 8; ++q) s += red[q][t];
    atomicAdd(&cn0[(long)z * 128 + f0 + t], s);
  }
  const int rr = t >> 3, cq = (t & 7) * 4;
  half4_t oh, ol;
  #pragma unroll
  for (int d = 0; d < 4; ++d) { oh[d] = sh[cq + d][rr]; ol[d] = sl[cq + d][rr]; }
  long ob = (long)z * 128 * N_NODES + (long)(f0 + rr) * N_NODES + m0 + cq;
  *(half4_t*)(TH + ob) = oh;
  *(half4_t*)(TL + ob) = ol;
}

// ---- fused mix+GEMM: partials[kc][ch][i][f] = (sum_e fw[off+ch*4+e] A_e) @ B[ch]
// One channel per block. Flat grid 512 = tile(64) + 64*ch(4) + 256*kc(2):
// all 8 A-sharers of a tile are bid == tile (mod 64) -> same XCD, co-resident.
// K=1024 per block (32 chunks of 32), dbuf LDS, one barrier per chunk.
__global__ __launch_bounds__(256, 2)
void gemm_mix_k(const float* __restrict__ A, const float* __restrict__ fw, int off,
                const _Float16* __restrict__ BH, const _Float16* __restrict__ BL,
                float* __restrict__ C) {
  __shared__ __align__(16) _Float16 Hs[2][2][1024];   // [buf][hl][32r x 32k swz]
  __shared__ __align__(16) _Float16 Bs[2][2][4096];   // [buf][hl][128f x 32k swz]

  const int t = threadIdx.x;
  const int lane = t & 63;
  const int w = t >> 6;
  const int bid = blockIdx.x;
  const int tile = bid & 63;
  const int ch = (bid >> 6) & 3;
  const int kc = bid >> 8;
  const int i0 = tile * 32;
  const long koff = (long)kc * 1024;

  float wv[4];
  #pragma unroll
  for (int e = 0; e < 4; ++e) wv[e] = fw[off + ch * 4 + e];

  // A per-thread source: row rr, k-cols k4..k4+3, all 4 e
  const int rr = t >> 3;                // 0..31
  const int k4 = (t & 7) * 4;           // 0..28
  const float* gA = A + (long)(i0 + rr) * N_NODES + koff + k4;
  // H store offset, k-group swizzle p = (g + (row>>1)) & 3
  const int hoff = rr * 32 + (((k4 >> 3) + (rr >> 1)) & 3) * 8 + (k4 & 7);

  // B staging: waves 0-1 -> BH halves, waves 2-3 -> BL halves; 4 cp16/lane/chunk
  const int hls = w >> 1;               // staged plane (0=H,1=L)
  const int half = w & 1;               // 64-row half
  const int kc_st = (((lane & 3) - ((lane >> 3) & 3)) & 3) * 8;
  const _Float16* gB = (hls ? BL : BH)
                     + ((long)ch * 128 + half * 64 + (lane >> 2)) * (long)N_NODES
                     + koff + kc_st;

  // MFMA fragment offsets
  const int wm = w >> 1, wn = w & 1;
  const int fr = lane & 15;
  const int fq = lane >> 4;
  const int fkz = ((fq + (fr >> 1)) & 3) * 8;
  const int aoff = (wm * 16 + fr) * 32 + fkz;

  floatx4 acc[4];
  #pragma unroll
  for (int j = 0; j < 4; ++j) {
    floatx4 zz4 = {0.f, 0.f, 0.f, 0.f};
    acc[j] = zz4;
  }

  const int NKT = 32;

  auto stageB = [&](int ktv, int pb) {
    _Float16* lb = &Bs[pb][hls][half * 2048];
    const _Float16* g = gB + ktv * 32;
    #pragma unroll
    for (int q = 0; q < 4; ++q)
      async_cp16(g + (long)q * (16L * N_NODES), lb + q * 512 + lane * 8);
  };
  auto mixStore = [&](const float4& a0, const float4& a1,
                      const float4& a2, const float4& a3, int pb) {
    float av0[4] = {a0.x, a0.y, a0.z, a0.w};
    float av1[4] = {a1.x, a1.y, a1.z, a1.w};
    float av2[4] = {a2.x, a2.y, a2.z, a2.w};
    float av3[4] = {a3.x, a3.y, a3.z, a3.w};
    half4_t h, l;
    #pragma unroll
    for (int d = 0; d < 4; ++d) {
      float o = wv[0] * av0[d] + wv[1] * av1[d] + wv[2] * av2[d] + wv[3] * av3[d];
      _Float16 hh = (_Float16)o;
      h[d] = hh; l[d] = (_Float16)(o - (float)hh);
    }
    *(half4_t*)&Hs[pb][0][hoff] = h;
    *(half4_t*)&Hs[pb][1][hoff] = l;
  };

  // prologue: chunk 0 -> buf 0
  {
    float4 a0 = *(const float4*)(gA);
    float4 a1 = *(const float4*)(gA + NNE);
    float4 a2 = *(const float4*)(gA + 2 * NNE);
    float4 a3 = *(const float4*)(gA + 3 * NNE);
    stageB(0, 0);
    mixStore(a0, a1, a2, a3, 0);
  }
  __syncthreads();

  for (int kt = 0; kt < NKT; ++kt) {
    const int p = kt & 1;
    float4 a0, a1, a2, a3;
    if (kt + 1 < NKT) {
      const float* g = gA + (kt + 1) * 32;
      a0 = *(const float4*)(g);
      a1 = *(const float4*)(g + NNE);
      a2 = *(const float4*)(g + 2 * NNE);
      a3 = *(const float4*)(g + 3 * NNE);
      stageB(kt + 1, p ^ 1);
    }
    // MFMA on buf p
    half8_t ah = *(const half8_t*)&Hs[p][0][aoff];
    half8_t al = *(const half8_t*)&Hs[p][1][aoff];
    #pragma unroll
    for (int nt = 0; nt < 4; ++nt) {
      const int bo = (wn * 64 + nt * 16 + fr) * 32 + fkz;
      half8_t bh = *(const half8_t*)&Bs[p][0][bo];
      half8_t bl = *(const half8_t*)&Bs[p][1][bo];
      acc[nt] = __builtin_amdgcn_mfma_f32_16x16x32_f16(ah, bh, acc[nt], 0, 0, 0);
      acc[nt] = __builtin_amdgcn_mfma_f32_16x16x32_f16(al, bh, acc[nt], 0, 0, 0);
      acc[nt] = __builtin_amdgcn_mfma_f32_16x16x32_f16(ah, bl, acc[nt], 0, 0, 0);
    }
    if (kt + 1 < NKT) mixStore(a0, a1, a2, a3, p ^ 1);
    __syncthreads();
  }

  const int er = fq * 4;
  const int ec = lane & 15;
  float* Cb = C + ((long)(kc * 4 + ch) * N_NODES + i0 + wm * 16) * 128;
  #pragma unroll
  for (int nt = 0; nt < 4; ++nt) {
    const int f = wn * 64 + nt * 16 + ec;
    #pragma unroll
    for (int r = 0; r < 4; ++r)
      Cb[(long)(er + r) * 128 + f] = acc[nt][r];
  }
}

// -- T'[z][f][j] = split( (sum_parts P[pp][z][j][f]) * s(cn_in[z][f]) ) -----
__global__ __launch_bounds__(256)
void combineT_k(const float* __restrict__ P, int parts,
                const float* __restrict__ cn_in, float* __restrict__ cn_out,
                _Float16* __restrict__ TH, _Float16* __restrict__ TL) {
  __shared__ _Float16 sh[32][33], sl[32][33];
  __shared__ float red[8][32];
  const int t = threadIdx.x;
  const int z = blockIdx.z;
  const int j0 = blockIdx.x * 32, f0 = blockIdx.y * 32;
  const int r0 = t >> 5, col = t & 31;
  const float s = colscale_from(cn_in[(long)z * 128 + f0 + col]);
  const long step = 4L * N_NODES * 128;
  float part = 0.f;
  #pragma unroll
  for (int m = 0; m < 4; ++m) {
    long idx = ((long)z * N_NODES + j0 + r0 + 8 * m) * 128 + f0 + col;
    float v = P[idx];
    for (int pp = 1; pp < parts; ++pp) v += P[idx + pp * step];
    v *= s;
    _Float16 h = (_Float16)v;
    sh[r0 + 8 * m][col] = h;
    sl[r0 + 8 * m][col] = (_Float16)(v - (float)h);
    part += fabsf(v);
  }
  if (cn_out) red[r0][col] = part;
  __syncthreads();
  if (cn_out && t < 32) {
    float ss = 0.f;
    #pragma unroll
    for (int q = 0; q < 8; ++q) ss += red[q][t];
    atomicAdd(&cn_out[(long)z * 128 + f0 + t], ss);
  }
  const int rr = t >> 3, cq = (t & 7) * 4;
  half4_t oh, ol;
  #pragma unroll
  for (int d = 0; d < 4; ++d) { oh[d] = sh[cq + d][rr]; ol[d] = sl[cq + d][rr]; }
  long ob = (long)z * 128 * N_NODES + (long)(f0 + rr) * N_NODES + j0 + cq;
  *(half4_t*)(TH + ob) = oh;
  *(half4_t*)(TL + ob) = ol;
}

// --- out[i][c*128+f] = relu( d*( T2sum * 2^(i0+i1-33) + supd ) + b ) -------
__global__ __launch_bounds__(256)
void final_k(const float4* __restrict__ T2, const float4* __restrict__ supd,
             const float* __restrict__ dvec, const float* __restrict__ cn0,
             const float* __restrict__ cn1, const float* __restrict__ bias,
             float* __restrict__ out) {
  const int t = threadIdx.x;
  const int z = blockIdx.y;
  const int idx = blockIdx.x * 256 + t;
  const int i = idx >> 5;
  const int fq = (idx & 31) * 4;
  const long step4 = 4L * N_NODES * 32;
  long b4 = (long)z * N_NODES * 32 + idx;
  float4 s0 = T2[b4];
  float4 s1 = T2[b4 + step4];
  float4 sp = supd[(long)z * N_NODES * 32 + idx];
  const float dn = dvec[(long)z * N_NODES + i];
  float inv[4];
  #pragma unroll
  for (int d = 0; d < 4; ++d) {
    int i0 = ilogbf(fmaxf(cn0[(long)z * 128 + fq + d], 1e-37f));
    int i1 = ilogbf(fmaxf(cn1[(long)z * 128 + fq + d], 1e-37f));
    inv[d] = exp2f((float)(i0 + i1 - 33));
  }
  float4 o;
  o.x = fmaxf(dn * ((s0.x + s1.x) * inv[0] + sp.x) + bias[fq + 0], 0.f);
  o.y = fmaxf(dn * ((s0.y + s1.y) * inv[1] + sp.y) + bias[fq + 1], 0.f);
  o.z = fmaxf(dn * ((s0.z + s1.z) * inv[2] + sp.z) + bias[fq + 2], 0.f);
  o.w = fmaxf(dn * ((s0.w + s1.w) * inv[3] + sp.w) + bias[fq + 3], 0.f);
  *(float4*)(out + (long)i * 512 + z * 128 + fq) = o;
}

extern "C" void kernel_launch(void* const* d_in, const int* in_sizes, int n_in,
                              void* d_out, int out_size, void* d_ws, size_t ws_size,
                              hipStream_t stream) {
  const float* A  = (const float*)d_in[0];
  const float* X  = (const float*)d_in[1];
  const float* w1 = (const float*)d_in[2];
  const float* w2 = (const float*)d_in[3];
  const float* w3 = (const float*)d_in[4];
  const float* gw = (const float*)d_in[5];
  const float* gb = (const float*)d_in[6];
  float* out = (float*)d_out;

  // ---- workspace layout (floats first, then f16 arena; all 16B aligned) ----
  float* ws   = (float*)d_ws;
  float* fw   = ws;                         // 64
  float* rc   = fw + 64;                    // 4*2048
  float* v1   = rc + 4 * N_NODES;           // 4*2048
  float* deg  = v1 + 4 * N_NODES;           // 4*2048
  float* dvec = deg + 4 * N_NODES;          // 4*2048
  float* sup  = dvec + 4 * N_NODES;         // 2048*128
  float* cn0  = sup + (long)N_NODES * 128;  // 512
  float* cn1  = cn0 + 512;                  // 512
  float* supd = cn1 + 512;                  // 4*2048*128
  float* Mtmp = supd + 4L * N_NODES * 128;  // [2kc][4ch][2048][128]
  _Float16* arena = (_Float16*)(Mtmp + 8L * N_NODES * 128);
  _Float16* VTH = arena;                    // [4][128][2048]
  _Float16* VTL = VTH + 4L * 128 * N_NODES;
  _Float16* T0H = VTL + 4L * 128 * N_NODES;
  _Float16* T0L = T0H + 4L * 128 * N_NODES;
  _Float16* T1H = T0L + 4L * 128 * N_NODES;
  _Float16* T1L = T1H + 4L * 128 * N_NODES;

  // ---- prework ----
  softmax3_zero_k<<<1, 256, 0, stream>>>(w1, w2, w3, fw, cn0);   // zeroes cn0+cn1
  support_k<<<N_NODES, 128, 0, stream>>>(X, gw, sup);
  // deg chain: rc = fw3-mix of rowsum(A_e); v1 = Hb@rc; deg = Ha@v1
  rc_from_A_k<<<N_NODES / 4, 256, 0, stream>>>(A, fw, rc);
  matvecA_k<<<N_NODES / 4, 256, 0, stream>>>(A, fw, 16, rc, v1);
  matvecA_k<<<N_NODES / 4, 256, 0, stream>>>(A, fw, 0, v1, deg);
  // supd = d .* support ; VT = (supd*2^13)^T split ; cn0 col 1-norms
  transposeV_k<<<dim3(64, 4, 4), 256, 0, stream>>>(sup, deg, dvec, supd,
                                                   VTH, VTL, cn0);
  // T0 = Hc @ VT   (mix-on-the-fly from A, fw offset 32)
  gemm_mix_k<<<512, 256, 0, stream>>>(A, fw, 32, VTH, VTL, Mtmp);
  combineT_k<<<dim3(64, 4, 4), 256, 0, stream>>>(Mtmp, 2, cn0, cn1, T0H, T0L);
  // T1 = Hb @ T0'  (fw offset 16)
  gemm_mix_k<<<512, 256, 0, stream>>>(A, fw, 16, T0H, T0L, Mtmp);
  combineT_k<<<dim3(64, 4, 4), 256, 0, stream>>>(Mtmp, 2, cn1, nullptr, T1H, T1L);
  // T2 = Ha @ T1'  (fw offset 0, fp32 partials)
  gemm_mix_k<<<512, 256, 0, stream>>>(A, fw, 0, T1H, T1L, Mtmp);
  // out = relu( d*(T2*inv + supd) + b )
  final_k<<<dim3(256, 4), 256, 0, stream>>>((const float4*)Mtmp,
                                            (const float4*)supd, dvec,
                                            cn0, cn1, gb, out);
}

// Round 4
// 259.715 us; speedup vs baseline: 1.1181x; 1.1181x over previous
//
#include <hip/hip_runtime.h>
#include <math.h>

#define N_NODES 2048
#define NNE ((long)N_NODES * N_NODES)   // elems per channel matrix

// f16 two-term split: x ~= h + l (true residual). Three MFMA products
// (hh, lh, hl) into ONE fp32 accumulator; dropped l*l term ~2^-22 relative.
// Scale chain (all powers of 2, exact):
//   V0' = supd * 2^13
//   T0  = Hc@V0'  -> scaled by sT0[f] = 2^(10-ilogb(cn0[f])), cn0=sum_m|V0'|
//   T1  = Hb@T0'  -> scaled by sT1[f] = 2^(10-ilogb(cn1[f])), cn1=sum_j|T0'|
//   T2  = Ha@T1'  (fp32); out = d*(T2*2^(i0+i1-33) + supd) + b
// H matrices never materialized: gemm_mix_k mixes A->H on the fly.
// R4: split-K 4 (grid 1024, 4 blk/CU — TLP hides the barrier drain);
//     deg chain at 1 row/block, 2048 blocks, no LDS staging (32 waves/CU).
#define SUPD_SCALE 8192.0f

typedef _Float16 half4_t __attribute__((ext_vector_type(4)));
typedef _Float16 half8_t __attribute__((ext_vector_type(8)));
typedef float    floatx4 __attribute__((ext_vector_type(4)));

__device__ __forceinline__ void async_cp16(const void* g, void* l) {
  __builtin_amdgcn_global_load_lds((const __attribute__((address_space(1))) void*)g,
                                   (__attribute__((address_space(3))) void*)l,
                                   16, 0, 0);
}

__device__ __forceinline__ float colscale_from(float cn) {
  return exp2f((float)(10 - ilogbf(fmaxf(cn, 1e-37f))));
}

// ---- softmax of the three 4x4 weight matrices + zero cn0/cn1 (1024 f) ----
__global__ void softmax3_zero_k(const float* __restrict__ w1,
                                const float* __restrict__ w2,
                                const float* __restrict__ w3,
                                float* __restrict__ fw,
                                float* __restrict__ cn) {
  int t = threadIdx.x;
  float4 z4 = {0.f, 0.f, 0.f, 0.f};
  ((float4*)cn)[t] = z4;                       // 256*4 = 1024 floats
  if (t < 12) {
    const float* src = (t < 4) ? w1 : (t < 8) ? w2 : w3;
    int r = t & 3;
    float v0 = src[r * 4 + 0], v1 = src[r * 4 + 1];
    float v2 = src[r * 4 + 2], v3 = src[r * 4 + 3];
    float m = fmaxf(fmaxf(v0, v1), fmaxf(v2, v3));
    float e0 = expf(v0 - m), e1 = expf(v1 - m), e2 = expf(v2 - m), e3 = expf(v3 - m);
    float inv = 1.0f / (e0 + e1 + e2 + e3);
    fw[t * 4 + 0] = e0 * inv; fw[t * 4 + 1] = e1 * inv;
    fw[t * 4 + 2] = e2 * inv; fw[t * 4 + 3] = e3 * inv;
  }
}

// ---------------- support = X @ gcn_w  [2048,256]@[256,128] ----------------
__global__ __launch_bounds__(128)
void support_k(const float* __restrict__ X, const float* __restrict__ W,
               float* __restrict__ sup) {
  __shared__ float Xs[256];
  const int t = threadIdx.x;
  const int m = blockIdx.x;
  Xs[t]       = X[(long)m * 256 + t];
  Xs[t + 128] = X[(long)m * 256 + t + 128];
  __syncthreads();
  float acc = 0.f;
  #pragma unroll 8
  for (int k = 0; k < 256; ++k) acc = fmaf(Xs[k], W[(long)k * 128 + t], acc);
  sup[(long)m * 128 + t] = acc;
}

// ---- rc[c][r] = sum_e fw3[c][e] * rowsum(A_e)[r] ----------
// One row per block; 4 waves split the j-range; mix folded before reduce.
__global__ __launch_bounds__(256)
void rc_from_A_k(const float* __restrict__ A, const float* __restrict__ fw,
                 float* __restrict__ rc) {
  __shared__ float red[4][4];
  const int r = blockIdx.x;
  const int w = threadIdx.x >> 6, lane = threadIdx.x & 63;
  float se[4];
  #pragma unroll
  for (int e = 0; e < 4; ++e) {
    const float4* row = (const float4*)(A + (long)e * NNE + (long)r * N_NODES);
    float s = 0.f;
    #pragma unroll
    for (int q = 0; q < 2; ++q) {
      float4 a = row[w * 128 + q * 64 + lane];
      s += (a.x + a.y) + (a.z + a.w);
    }
    se[e] = s;
  }
  float m[4];
  #pragma unroll
  for (int c = 0; c < 4; ++c)
    m[c] = fw[32 + c * 4 + 0] * se[0] + fw[32 + c * 4 + 1] * se[1] +
           fw[32 + c * 4 + 2] * se[2] + fw[32 + c * 4 + 3] * se[3];
  #pragma unroll
  for (int o = 32; o > 0; o >>= 1) {
    #pragma unroll
    for (int c = 0; c < 4; ++c) m[c] += __shfl_down(m[c], o, 64);
  }
  if (lane == 0) {
    #pragma unroll
    for (int c = 0; c < 4; ++c) red[w][c] = m[c];
  }
  __syncthreads();
  if (threadIdx.x < 4) {
    int c = threadIdx.x;
    rc[c * N_NODES + r] = (red[0][c] + red[1][c]) + (red[2][c] + red[3][c]);
  }
}

// -- vout[c][r] = sum_e fw[off+c*4+e] * (A_e @ vin[c])[r]  (fp32) ----------
// One row per block; 4 waves split j; vin read direct (32 KB, L2-hot).
__global__ __launch_bounds__(256)
void matvecA_k(const float* __restrict__ A, const float* __restrict__ fw, int off,
               const float* __restrict__ vin, float* __restrict__ vout) {
  __shared__ float red[4][4];
  const int r = blockIdx.x;
  const int w = threadIdx.x >> 6, lane = threadIdx.x & 63;
  float acc[4][4] = {{0.f}};
  #pragma unroll
  for (int q = 0; q < 2; ++q) {
    const int j4 = w * 128 + q * 64 + lane;
    float4 v0 = *(const float4*)&vin[0 * 2048 + j4 * 4];
    float4 v1 = *(const float4*)&vin[1 * 2048 + j4 * 4];
    float4 v2 = *(const float4*)&vin[2 * 2048 + j4 * 4];
    float4 v3 = *(const float4*)&vin[3 * 2048 + j4 * 4];
    #pragma unroll
    for (int e = 0; e < 4; ++e) {
      float4 a = *(const float4*)(A + (long)e * NNE + (long)r * N_NODES + j4 * 4);
      acc[e][0] += (a.x * v0.x + a.y * v0.y) + (a.z * v0.z + a.w * v0.w);
      acc[e][1] += (a.x * v1.x + a.y * v1.y) + (a.z * v1.z + a.w * v1.w);
      acc[e][2] += (a.x * v2.x + a.y * v2.y) + (a.z * v2.z + a.w * v2.w);
      acc[e][3] += (a.x * v3.x + a.y * v3.y) + (a.z * v3.z + a.w * v3.w);
    }
  }
  float m[4];
  #pragma unroll
  for (int c = 0; c < 4; ++c)
    m[c] = fw[off + c * 4 + 0] * acc[0][c] + fw[off + c * 4 + 1] * acc[1][c] +
           fw[off + c * 4 + 2] * acc[2][c] + fw[off + c * 4 + 3] * acc[3][c];
  #pragma unroll
  for (int o = 32; o > 0; o >>= 1) {
    #pragma unroll
    for (int c = 0; c < 4; ++c) m[c] += __shfl_down(m[c], o, 64);
  }
  if (lane == 0) {
    #pragma unroll
    for (int c = 0; c < 4; ++c) red[w][c] = m[c];
  }
  __syncthreads();
  if (threadIdx.x < 4) {
    int c = threadIdx.x;
    vout[c * N_NODES + r] = (red[0][c] + red[1][c]) + (red[2][c] + red[3][c]);
  }
}

// -- fused: dm = 1/sqrt(1+deg); supd = dm*sup (side output, + dvec);
// -- VT[z][f][m] = split( supd*2^13 ); cn0[z][f] += sum_m |val| ------------
__global__ __launch_bounds__(256)
void transposeV_k(const float* __restrict__ sup, const float* __restrict__ deg,
                  float* __restrict__ dvec, float* __restrict__ supd,
                  _Float16* __restrict__ TH, _Float16* __restrict__ TL,
                  float* __restrict__ cn0) {
  __shared__ _Float16 sh[32][33], sl[32][33];
  __shared__ float red[8][32];
  const int t = threadIdx.x;
  const int z = blockIdx.z;
  const int m0 = blockIdx.x * 32, f0 = blockIdx.y * 32;
  const int r0 = t >> 5, col = t & 31;
  float part = 0.f;
  #pragma unroll
  for (int m = 0; m < 4; ++m) {
    const int row = m0 + r0 + 8 * m;
    float dm = 1.0f / sqrtf(1.0f + deg[(long)z * N_NODES + row]);
    float sv = sup[(long)row * 128 + f0 + col] * dm;
    supd[((long)z * N_NODES + row) * 128 + f0 + col] = sv;
    if (blockIdx.y == 0 && col == 0) dvec[(long)z * N_NODES + row] = dm;
    float v = sv * SUPD_SCALE;
    _Float16 h = (_Float16)v;
    sh[r0 + 8 * m][col] = h;
    sl[r0 + 8 * m][col] = (_Float16)(v - (float)h);
    part += fabsf(v);
  }
  red[r0][col] = part;
  __syncthreads();
  if (t < 32) {
    float s = 0.f;
    #pragma unroll
    for (int q = 0; q < 8; ++q) s += red[q][t];
    atomicAdd(&cn0[(long)z * 128 + f0 + t], s);
  }
  const int rr = t >> 3, cq = (t & 7) * 4;
  half4_t oh, ol;
  #pragma unroll
  for (int d = 0; d < 4; ++d) { oh[d] = sh[cq + d][rr]; ol[d] = sl[cq + d][rr]; }
  long ob = (long)z * 128 * N_NODES + (long)(f0 + rr) * N_NODES + m0 + cq;
  *(half4_t*)(TH + ob) = oh;
  *(half4_t*)(TL + ob) = ol;
}

// ---- fused mix+GEMM: partials[kc][ch][i][f] = (sum_e fw[off+ch*4+e] A_e) @ B[ch]
// One channel per block. Flat grid 1024 = tile(64) + 64*ch(4) + 256*kc(4):
// all A-sharers of a tile are bid == tile (mod 64) -> same XCD, co-resident.
// K=512 per block (16 chunks of 32), dbuf LDS 40KB -> 4 blk/CU (LDS-exact).
__global__ __launch_bounds__(256, 4)
void gemm_mix_k(const float* __restrict__ A, const float* __restrict__ fw, int off,
                const _Float16* __restrict__ BH, const _Float16* __restrict__ BL,
                float* __restrict__ C) {
  __shared__ __align__(16) _Float16 Hs[2][2][1024];   // [buf][hl][32r x 32k swz]
  __shared__ __align__(16) _Float16 Bs[2][2][4096];   // [buf][hl][128f x 32k swz]

  const int t = threadIdx.x;
  const int lane = t & 63;
  const int w = t >> 6;
  const int bid = blockIdx.x;
  const int tile = bid & 63;
  const int ch = (bid >> 6) & 3;
  const int kc = bid >> 8;              // 0..3
  const int i0 = tile * 32;
  const long koff = (long)kc * 512;

  float wv[4];
  #pragma unroll
  for (int e = 0; e < 4; ++e) wv[e] = fw[off + ch * 4 + e];

  // A per-thread source: row rr, k-cols k4..k4+3, all 4 e
  const int rr = t >> 3;                // 0..31
  const int k4 = (t & 7) * 4;           // 0..28
  const float* gA = A + (long)(i0 + rr) * N_NODES + koff + k4;
  // H store offset, k-group swizzle p = (g + (row>>1)) & 3
  const int hoff = rr * 32 + (((k4 >> 3) + (rr >> 1)) & 3) * 8 + (k4 & 7);

  // B staging: waves 0-1 -> BH halves, waves 2-3 -> BL halves; 4 cp16/lane/chunk
  const int hls = w >> 1;               // staged plane (0=H,1=L)
  const int half = w & 1;               // 64-row half
  const int kc_st = (((lane & 3) - ((lane >> 3) & 3)) & 3) * 8;
  const _Float16* gB = (hls ? BL : BH)
                     + ((long)ch * 128 + half * 64 + (lane >> 2)) * (long)N_NODES
                     + koff + kc_st;

  // MFMA fragment offsets
  const int wm = w >> 1, wn = w & 1;
  const int fr = lane & 15;
  const int fq = lane >> 4;
  const int fkz = ((fq + (fr >> 1)) & 3) * 8;
  const int aoff = (wm * 16 + fr) * 32 + fkz;

  floatx4 acc[4];
  #pragma unroll
  for (int j = 0; j < 4; ++j) {
    floatx4 zz4 = {0.f, 0.f, 0.f, 0.f};
    acc[j] = zz4;
  }

  const int NKT = 16;

  auto stageB = [&](int ktv, int pb) {
    _Float16* lb = &Bs[pb][hls][half * 2048];
    const _Float16* g = gB + ktv * 32;
    #pragma unroll
    for (int q = 0; q < 4; ++q)
      async_cp16(g + (long)q * (16L * N_NODES), lb + q * 512 + lane * 8);
  };
  auto mixStore = [&](const float4& a0, const float4& a1,
                      const float4& a2, const float4& a3, int pb) {
    float av0[4] = {a0.x, a0.y, a0.z, a0.w};
    float av1[4] = {a1.x, a1.y, a1.z, a1.w};
    float av2[4] = {a2.x, a2.y, a2.z, a2.w};
    float av3[4] = {a3.x, a3.y, a3.z, a3.w};
    half4_t h, l;
    #pragma unroll
    for (int d = 0; d < 4; ++d) {
      float o = wv[0] * av0[d] + wv[1] * av1[d] + wv[2] * av2[d] + wv[3] * av3[d];
      _Float16 hh = (_Float16)o;
      h[d] = hh; l[d] = (_Float16)(o - (float)hh);
    }
    *(half4_t*)&Hs[pb][0][hoff] = h;
    *(half4_t*)&Hs[pb][1][hoff] = l;
  };

  // prologue: chunk 0 -> buf 0
  {
    float4 a0 = *(const float4*)(gA);
    float4 a1 = *(const float4*)(gA + NNE);
    float4 a2 = *(const float4*)(gA + 2 * NNE);
    float4 a3 = *(const float4*)(gA + 3 * NNE);
    stageB(0, 0);
    mixStore(a0, a1, a2, a3, 0);
  }
  __syncthreads();

  for (int kt = 0; kt < NKT; ++kt) {
    const int p = kt & 1;
    float4 a0, a1, a2, a3;
    if (kt + 1 < NKT) {
      const float* g = gA + (kt + 1) * 32;
      a0 = *(const float4*)(g);
      a1 = *(const float4*)(g + NNE);
      a2 = *(const float4*)(g + 2 * NNE);
      a3 = *(const float4*)(g + 3 * NNE);
      stageB(kt + 1, p ^ 1);
    }
    // MFMA on buf p
    half8_t ah = *(const half8_t*)&Hs[p][0][aoff];
    half8_t al = *(const half8_t*)&Hs[p][1][aoff];
    #pragma unroll
    for (int nt = 0; nt < 4; ++nt) {
      const int bo = (wn * 64 + nt * 16 + fr) * 32 + fkz;
      half8_t bh = *(const half8_t*)&Bs[p][0][bo];
      half8_t bl = *(const half8_t*)&Bs[p][1][bo];
      acc[nt] = __builtin_amdgcn_mfma_f32_16x16x32_f16(ah, bh, acc[nt], 0, 0, 0);
      acc[nt] = __builtin_amdgcn_mfma_f32_16x16x32_f16(al, bh, acc[nt], 0, 0, 0);
      acc[nt] = __builtin_amdgcn_mfma_f32_16x16x32_f16(ah, bl, acc[nt], 0, 0, 0);
    }
    if (kt + 1 < NKT) mixStore(a0, a1, a2, a3, p ^ 1);
    __syncthreads();
  }

  const int er = fq * 4;
  const int ec = lane & 15;
  float* Cb = C + ((long)(kc * 4 + ch) * N_NODES + i0 + wm * 16) * 128;
  #pragma unroll
  for (int nt = 0; nt < 4; ++nt) {
    const int f = wn * 64 + nt * 16 + ec;
    #pragma unroll
    for (int r = 0; r < 4; ++r)
      Cb[(long)(er + r) * 128 + f] = acc[nt][r];
  }
}

// -- T'[z][f][j] = split( (sum_parts P[pp][z][j][f]) * s(cn_in[z][f]) ) -----
__global__ __launch_bounds__(256)
void combineT_k(const float* __restrict__ P, int parts,
                const float* __restrict__ cn_in, float* __restrict__ cn_out,
                _Float16* __restrict__ TH, _Float16* __restrict__ TL) {
  __shared__ _Float16 sh[32][33], sl[32][33];
  __shared__ float red[8][32];
  const int t = threadIdx.x;
  const int z = blockIdx.z;
  const int j0 = blockIdx.x * 32, f0 = blockIdx.y * 32;
  const int r0 = t >> 5, col = t & 31;
  const float s = colscale_from(cn_in[(long)z * 128 + f0 + col]);
  const long step = 4L * N_NODES * 128;
  float part = 0.f;
  #pragma unroll
  for (int m = 0; m < 4; ++m) {
    long idx = ((long)z * N_NODES + j0 + r0 + 8 * m) * 128 + f0 + col;
    float v = (P[idx] + P[idx + step]) + (P[idx + 2 * step] + P[idx + 3 * step]);
    v *= s;
    _Float16 h = (_Float16)v;
    sh[r0 + 8 * m][col] = h;
    sl[r0 + 8 * m][col] = (_Float16)(v - (float)h);
    part += fabsf(v);
  }
  if (cn_out) red[r0][col] = part;
  __syncthreads();
  if (cn_out && t < 32) {
    float ss = 0.f;
    #pragma unroll
    for (int q = 0; q < 8; ++q) ss += red[q][t];
    atomicAdd(&cn_out[(long)z * 128 + f0 + t], ss);
  }
  const int rr = t >> 3, cq = (t & 7) * 4;
  half4_t oh, ol;
  #pragma unroll
  for (int d = 0; d < 4; ++d) { oh[d] = sh[cq + d][rr]; ol[d] = sl[cq + d][rr]; }
  long ob = (long)z * 128 * N_NODES + (long)(f0 + rr) * N_NODES + j0 + cq;
  *(half4_t*)(TH + ob) = oh;
  *(half4_t*)(TL + ob) = ol;
}

// --- out[i][c*128+f] = relu( d*( T2sum * 2^(i0+i1-33) + supd ) + b ) -------
__global__ __launch_bounds__(256)
void final_k(const float4* __restrict__ T2, const float4* __restrict__ supd,
             const float* __restrict__ dvec, const float* __restrict__ cn0,
             const float* __restrict__ cn1, const float* __restrict__ bias,
             float* __restrict__ out) {
  const int t = threadIdx.x;
  const int z = blockIdx.y;
  const int idx = blockIdx.x * 256 + t;
  const int i = idx >> 5;
  const int fq = (idx & 31) * 4;
  const long step4 = 4L * N_NODES * 32;
  long b4 = (long)z * N_NODES * 32 + idx;
  float4 s0 = T2[b4];
  float4 s1 = T2[b4 + step4];
  float4 s2 = T2[b4 + 2 * step4];
  float4 s3 = T2[b4 + 3 * step4];
  float4 sp = supd[(long)z * N_NODES * 32 + idx];
  const float dn = dvec[(long)z * N_NODES + i];
  float inv[4];
  #pragma unroll
  for (int d = 0; d < 4; ++d) {
    int i0 = ilogbf(fmaxf(cn0[(long)z * 128 + fq + d], 1e-37f));
    int i1 = ilogbf(fmaxf(cn1[(long)z * 128 + fq + d], 1e-37f));
    inv[d] = exp2f((float)(i0 + i1 - 33));
  }
  float4 o;
  o.x = fmaxf(dn * (((s0.x + s1.x) + (s2.x + s3.x)) * inv[0] + sp.x) + bias[fq + 0], 0.f);
  o.y = fmaxf(dn * (((s0.y + s1.y) + (s2.y + s3.y)) * inv[1] + sp.y) + bias[fq + 1], 0.f);
  o.z = fmaxf(dn * (((s0.z + s1.z) + (s2.z + s3.z)) * inv[2] + sp.z) + bias[fq + 2], 0.f);
  o.w = fmaxf(dn * (((s0.w + s1.w) + (s2.w + s3.w)) * inv[3] + sp.w) + bias[fq + 3], 0.f);
  *(float4*)(out + (long)i * 512 + z * 128 + fq) = o;
}

extern "C" void kernel_launch(void* const* d_in, const int* in_sizes, int n_in,
                              void* d_out, int out_size, void* d_ws, size_t ws_size,
                              hipStream_t stream) {
  const float* A  = (const float*)d_in[0];
  const float* X  = (const float*)d_in[1];
  const float* w1 = (const float*)d_in[2];
  const float* w2 = (const float*)d_in[3];
  const float* w3 = (const float*)d_in[4];
  const float* gw = (const float*)d_in[5];
  const float* gb = (const float*)d_in[6];
  float* out = (float*)d_out;

  // ---- workspace layout (floats first, then f16 arena; all 16B aligned) ----
  float* ws   = (float*)d_ws;
  float* fw   = ws;                         // 64
  float* rc   = fw + 64;                    // 4*2048
  float* v1   = rc + 4 * N_NODES;           // 4*2048
  float* deg  = v1 + 4 * N_NODES;           // 4*2048
  float* dvec = deg + 4 * N_NODES;          // 4*2048
  float* sup  = dvec + 4 * N_NODES;         // 2048*128
  float* cn0  = sup + (long)N_NODES * 128;  // 512
  float* cn1  = cn0 + 512;                  // 512
  float* supd = cn1 + 512;                  // 4*2048*128
  float* Mtmp = supd + 4L * N_NODES * 128;  // [4kc][4ch][2048][128]
  _Float16* arena = (_Float16*)(Mtmp + 16L * N_NODES * 128);
  _Float16* VTH = arena;                    // [4][128][2048]
  _Float16* VTL = VTH + 4L * 128 * N_NODES;
  _Float16* T0H = VTL + 4L * 128 * N_NODES;
  _Float16* T0L = T0H + 4L * 128 * N_NODES;
  _Float16* T1H = T0L + 4L * 128 * N_NODES;
  _Float16* T1L = T1H + 4L * 128 * N_NODES;

  // ---- prework ----
  softmax3_zero_k<<<1, 256, 0, stream>>>(w1, w2, w3, fw, cn0);   // zeroes cn0+cn1
  support_k<<<N_NODES, 128, 0, stream>>>(X, gw, sup);
  // deg chain: rc = fw3-mix of rowsum(A_e); v1 = Hb@rc; deg = Ha@v1
  rc_from_A_k<<<N_NODES, 256, 0, stream>>>(A, fw, rc);
  matvecA_k<<<N_NODES, 256, 0, stream>>>(A, fw, 16, rc, v1);
  matvecA_k<<<N_NODES, 256, 0, stream>>>(A, fw, 0, v1, deg);
  // supd = d .* support ; VT = (supd*2^13)^T split ; cn0 col 1-norms
  transposeV_k<<<dim3(64, 4, 4), 256, 0, stream>>>(sup, deg, dvec, supd,
                                                   VTH, VTL, cn0);
  // T0 = Hc @ VT   (mix-on-the-fly from A, fw offset 32)
  gemm_mix_k<<<1024, 256, 0, stream>>>(A, fw, 32, VTH, VTL, Mtmp);
  combineT_k<<<dim3(64, 4, 4), 256, 0, stream>>>(Mtmp, 4, cn0, cn1, T0H, T0L);
  // T1 = Hb @ T0'  (fw offset 16)
  gemm_mix_k<<<1024, 256, 0, stream>>>(A, fw, 16, T0H, T0L, Mtmp);
  combineT_k<<<dim3(64, 4, 4), 256, 0, stream>>>(Mtmp, 4, cn1, nullptr, T1H, T1L);
  // T2 = Ha @ T1'  (fw offset 0, fp32 partials)
  gemm_mix_k<<<1024, 256, 0, stream>>>(A, fw, 0, T1H, T1L, Mtmp);
  // out = relu( d*(T2*inv + supd) + b )
  final_k<<<dim3(256, 4), 256, 0, stream>>>((const float4*)Mtmp,
                                            (const float4*)supd, dvec,
                                            cn0, cn1, gb, out);
}